// Round 12
// baseline (267.146 us; speedup 1.0000x reference)
//
#include <hip/hip_runtime.h>

// (B,C,H,W)=(32,32,64,64), D=32, K=512
#define C_    32
#define D_    32
#define K_    512
#define HW_   4096
#define NTOK  131072
#define IDX_OFF   4194304
#define LOSS_OFF  4325376
#define TAU   2e-4f
#define WAVES 16      // waves per block; 512 tokens/block; real grid = 256 = 1 block/CU

// ws: cbn @0 (2KB), cbhf @4096 (32KB), cblf @36864 (32KB), lossp @69632 (16KB)
#define WS_CBN   0
#define WS_CBHF  4096
#define WS_CBLF  36864
#define WS_LOSSP 69632
#define WS_NEEDED 86016

typedef __attribute__((ext_vector_type(8))) _Float16 f16x8;
typedef __attribute__((ext_vector_type(8))) short    short8;
typedef __attribute__((ext_vector_type(4))) float    f32x4;

#define WAVE_FENCE() do { asm volatile("s_waitcnt lgkmcnt(0)" ::: "memory"); \
                          __builtin_amdgcn_sched_barrier(0); } while (0)

__device__ inline short f2h_hi(float v, float* rest) {
    const _Float16 h = (_Float16)v;
    *rest = v - (float)h;
    return __builtin_bit_cast(short, h);
}

// ---------- codebook: norms + f16 hi/lo split in FRAG-MAJOR layout ----------
__global__ __launch_bounds__(256)
void prep_cb(const float* __restrict__ cb, float* __restrict__ cbn,
             short* __restrict__ cbhf, short* __restrict__ cblf)
{
    const int k = blockIdx.x * 256 + threadIdx.x;   // grid=2 -> k in [0,512)
    const int nt = k >> 4, lr = k & 15;
    const float* row = cb + k * D_;
    float s = 0.f;
    short h[32], lo[32];
    #pragma unroll
    for (int d = 0; d < D_; ++d) {
        const float v = row[d]; s = fmaf(v, v, s);
        float r; h[d] = f2h_hi(v, &r);
        lo[d] = __builtin_bit_cast(short, (_Float16)r);
    }
    cbn[k] = s;
    #pragma unroll
    for (int j = 0; j < 4; ++j) {
        *(short8*)(cbhf + nt * 512 + (j * 16 + lr) * 8) = *(const short8*)(h  + 8 * j);
        *(short8*)(cblf + nt * 512 + (j * 16 + lr) * 8) = *(const short8*)(lo + 8 * j);
    }
}

// ---------- probe/real kernel. V=0 full; V=1 no-scan; V=2 min-only tracker; V=3 V2 minus LDS ----------
template<int V>
__global__ __launch_bounds__(1024, 4)
void vq_probe(const float* __restrict__ z,  const float* __restrict__ qw,
              const float* __restrict__ qb, const float* __restrict__ cb,
              const float* __restrict__ pw, const float* __restrict__ pb,
              const short* __restrict__ cbhf, const short* __restrict__ cblf,
              const float* __restrict__ cbn, float* __restrict__ lossp,
              float* __restrict__ out)
{
    __shared__ __align__(16) short cbh_s[16384];
    __shared__ __align__(16) short cbl_s[16384];
    __shared__ float cbn_s[K_];
    __shared__ float xsh[WAVES][32][33];
    __shared__ int   sidx[WAVES][32];

    const int tid = threadIdx.x;
    const int wv = tid >> 6, l = tid & 63;

    // ---- stage codebook to LDS ----
    #pragma unroll
    for (int i = 0; i < 2; ++i)
        ((float4*)cbh_s)[tid + 1024 * i] = ((const float4*)cbhf)[tid + 1024 * i];
    #pragma unroll
    for (int i = 0; i < 2; ++i)
        ((float4*)cbl_s)[tid + 1024 * i] = ((const float4*)cblf)[tid + 1024 * i];
    if (tid < K_) cbn_s[tid] = cbn[tid];
    __syncthreads();

    const int T0 = (blockIdx.x * WAVES + wv) * 32;
    const int b = T0 >> 12, hw0 = T0 & (HW_ - 1);
    const int tok = l & 31, half = l >> 5;

    // ---- phase 1: quant conv ----
    {
        const float* zbase = z + (size_t)b * (C_ * HW_) + hw0 + tok;
        float zv[C_];
        #pragma unroll
        for (int c = 0; c < C_; ++c) zv[c] = zbase[(size_t)c * HW_];
        const int d0 = half * 16;
        #pragma unroll
        for (int i = 0; i < 16; ++i) {
            float a = qb[d0 + i];
            const float4* qr = (const float4*)(qw + (d0 + i) * C_);
            #pragma unroll
            for (int c4 = 0; c4 < 8; ++c4) {
                const float4 q4 = qr[c4];
                a = fmaf(zv[4*c4+0], q4.x, a); a = fmaf(zv[4*c4+1], q4.y, a);
                a = fmaf(zv[4*c4+2], q4.z, a); a = fmaf(zv[4*c4+3], q4.w, a);
            }
            xsh[wv][tok][d0 + i] = a;
        }
    }
    WAVE_FENCE();

    // ---- A fragments ----
    const int lr = l & 15, lg = l >> 4;
    short8 sh0, sl0, sh1, sl1;
    #pragma unroll
    for (int j = 0; j < 8; ++j) {
        float r0, r1;
        sh0[j] = f2h_hi(xsh[wv][lr][lg * 8 + j], &r0);
        sl0[j] = __builtin_bit_cast(short, (_Float16)r0);
        sh1[j] = f2h_hi(xsh[wv][16 + lr][lg * 8 + j], &r1);
        sl1[j] = __builtin_bit_cast(short, (_Float16)r1);
    }
    const f16x8 ah0 = __builtin_bit_cast(f16x8, sh0);
    const f16x8 al0 = __builtin_bit_cast(f16x8, sl0);
    const f16x8 ah1 = __builtin_bit_cast(f16x8, sh1);
    const f16x8 al1 = __builtin_bit_cast(f16x8, sl1);

    if constexpr (V == 1) {
        // ---- no scan: deterministic fake indices ----
        if (l < 32) sidx[wv][l] = l;
        WAVE_FENCE();
    } else if constexpr (V == 0) {
        // ---- full scan: top-2 tracker ----
        float b1[8], b2[8]; int i1[8];
        #pragma unroll
        for (int s = 0; s < 8; ++s) { b1[s] = 3.4e38f; b2[s] = 3.4e38f; i1[s] = 0; }

        #pragma unroll 2
        for (int nt = 0; nt < 32; ++nt) {
            const f16x8 bh = __builtin_bit_cast(f16x8, *(const short8*)(cbh_s + nt * 512 + l * 8));
            const f16x8 bl = __builtin_bit_cast(f16x8, *(const short8*)(cbl_s + nt * 512 + l * 8));
            const float cn = cbn_s[nt * 16 + lr];
            f32x4 acc0 = {0.f,0.f,0.f,0.f}, acc1 = {0.f,0.f,0.f,0.f};
            acc0 = __builtin_amdgcn_mfma_f32_16x16x32_f16(ah0, bh, acc0, 0, 0, 0);
            acc0 = __builtin_amdgcn_mfma_f32_16x16x32_f16(ah0, bl, acc0, 0, 0, 0);
            acc0 = __builtin_amdgcn_mfma_f32_16x16x32_f16(al0, bh, acc0, 0, 0, 0);
            acc1 = __builtin_amdgcn_mfma_f32_16x16x32_f16(ah1, bh, acc1, 0, 0, 0);
            acc1 = __builtin_amdgcn_mfma_f32_16x16x32_f16(ah1, bl, acc1, 0, 0, 0);
            acc1 = __builtin_amdgcn_mfma_f32_16x16x32_f16(al1, bh, acc1, 0, 0, 0);
            const int n = nt * 16 + lr;
            #pragma unroll
            for (int r = 0; r < 4; ++r) {
                {
                    const float d2 = fmaf(-2.f, acc0[r], cn);
                    const bool lt1 = d2 < b1[r], lt2 = d2 < b2[r];
                    b2[r] = lt1 ? b1[r] : (lt2 ? d2 : b2[r]);
                    b1[r] = lt1 ? d2 : b1[r];
                    i1[r] = lt1 ? n  : i1[r];
                }
                {
                    const float d2 = fmaf(-2.f, acc1[r], cn);
                    const bool lt1 = d2 < b1[4+r], lt2 = d2 < b2[4+r];
                    b2[4+r] = lt1 ? b1[4+r] : (lt2 ? d2 : b2[4+r]);
                    b1[4+r] = lt1 ? d2 : b1[4+r];
                    i1[4+r] = lt1 ? n  : i1[4+r];
                }
            }
        }
        #pragma unroll
        for (int mk = 1; mk < 16; mk <<= 1) {
            #pragma unroll
            for (int s = 0; s < 8; ++s) {
                const float ob1 = __shfl_xor(b1[s], mk);
                const int   oi1 = __shfl_xor(i1[s], mk);
                const float ob2 = __shfl_xor(b2[s], mk);
                const bool take = (ob1 < b1[s]) || (ob1 == b1[s] && oi1 < i1[s]);
                const float loser = take ? b1[s] : ob1;
                b1[s] = take ? ob1 : b1[s];
                i1[s] = take ? oi1 : i1[s];
                b2[s] = fminf(fminf(b2[s], ob2), loser);
            }
        }
        #pragma unroll
        for (int s = 0; s < 8; ++s) {
            if (lr == s) {
                const int tokW = (s >> 2) * 16 + lg * 4 + (s & 3);
                sidx[wv][tokW] = i1[s] | (((b2[s] - b1[s]) < TAU) ? 512 : 0);
            }
        }
        WAVE_FENCE();
        // rescan of flagged tokens (exact fp32)
        {
            const int sv = sidx[wv][tok];
            unsigned long long m = __ballot((l < 32) && (sv & 512));
            while (m) {
                const int j = __ffsll(m) - 1; m &= m - 1;
                float xfj[D_];
                #pragma unroll
                for (int d = 0; d < D_; ++d) xfj[d] = xsh[wv][j][d];
                float bb = 3.4e38f; int bi = 0;
                #pragma unroll
                for (int p = 0; p < 8; ++p) {
                    const int c = l + 64 * p;
                    const float* row = cb + (size_t)c * D_;
                    float p0 = 0.f, p1 = 0.f, p2 = 0.f, p3 = 0.f;
                    #pragma unroll
                    for (int d = 0; d < D_; d += 4) {
                        p0 = fmaf(xfj[d],   row[d],   p0); p1 = fmaf(xfj[d+1], row[d+1], p1);
                        p2 = fmaf(xfj[d+2], row[d+2], p2); p3 = fmaf(xfj[d+3], row[d+3], p3);
                    }
                    const float dd = fmaf(-2.f, (p0 + p1) + (p2 + p3), cbn_s[c]);
                    if (dd < bb) { bb = dd; bi = c; }
                }
                #pragma unroll
                for (int s = 1; s < 64; s <<= 1) {
                    const float ob = __shfl_xor(bb, s); const int oi = __shfl_xor(bi, s);
                    if (ob < bb || (ob == bb && oi < bi)) { bb = ob; bi = oi; }
                }
                if (l == j) sidx[wv][j] = bi;
            }
        }
        WAVE_FENCE();
    } else {
        // ---- V2/V3: min-only tracker; V3 additionally removes all LDS reads from the loop ----
        float bm[8];
        #pragma unroll
        for (int s = 0; s < 8; ++s) bm[s] = 3.4e38f;

        #pragma unroll 2
        for (int nt = 0; nt < 32; ++nt) {
            f16x8 bh, bl; float cn;
            if constexpr (V == 2) {
                bh = __builtin_bit_cast(f16x8, *(const short8*)(cbh_s + nt * 512 + l * 8));
                bl = __builtin_bit_cast(f16x8, *(const short8*)(cbl_s + nt * 512 + l * 8));
                cn = cbn_s[nt * 16 + lr];
            } else {
                short8 t = sh0; t[0] = (short)(t[0] ^ nt);        // defeat CSE, no LDS
                short8 u = sl0; u[0] = (short)(u[0] ^ (nt + 7));
                bh = __builtin_bit_cast(f16x8, t);
                bl = __builtin_bit_cast(f16x8, u);
                cn = (float)nt * 1e-3f;
            }
            f32x4 acc0 = {0.f,0.f,0.f,0.f}, acc1 = {0.f,0.f,0.f,0.f};
            acc0 = __builtin_amdgcn_mfma_f32_16x16x32_f16(ah0, bh, acc0, 0, 0, 0);
            acc0 = __builtin_amdgcn_mfma_f32_16x16x32_f16(ah0, bl, acc0, 0, 0, 0);
            acc0 = __builtin_amdgcn_mfma_f32_16x16x32_f16(al0, bh, acc0, 0, 0, 0);
            acc1 = __builtin_amdgcn_mfma_f32_16x16x32_f16(ah1, bh, acc1, 0, 0, 0);
            acc1 = __builtin_amdgcn_mfma_f32_16x16x32_f16(ah1, bl, acc1, 0, 0, 0);
            acc1 = __builtin_amdgcn_mfma_f32_16x16x32_f16(al1, bh, acc1, 0, 0, 0);
            #pragma unroll
            for (int r = 0; r < 4; ++r) {
                bm[r]   = fminf(bm[r],   fmaf(-2.f, acc0[r], cn));
                bm[4+r] = fminf(bm[4+r], fmaf(-2.f, acc1[r], cn));
            }
        }
        #pragma unroll
        for (int s = 0; s < 8; ++s) {
            if (lr == s) {
                const int tokW = (s >> 2) * 16 + lg * 4 + (s & 3);
                float t = bm[0];
                #pragma unroll
                for (int q = 1; q < 8; ++q) t = fminf(t, bm[q]);
                sidx[wv][tokW] = (int)(__builtin_bit_cast(unsigned, t) & 511u);
            }
        }
        WAVE_FENCE();
    }

    const int myidx = sidx[wv][tok] & 511;

    // ---- phase 4: gather, loss, idx write, post conv (identical all variants) ----
    if (l < 32) out[IDX_OFF + T0 + l] = (float)(sidx[wv][l] & 511);

    float qreg[16];
    {
        const float4* qrow = (const float4*)(cb + (size_t)myidx * D_ + half * 16);
        #pragma unroll
        for (int d4 = 0; d4 < 4; ++d4) {
            const float4 t = qrow[d4];
            qreg[4*d4+0] = t.x; qreg[4*d4+1] = t.y; qreg[4*d4+2] = t.z; qreg[4*d4+3] = t.w;
        }
    }
    float lacc = 0.f;
    #pragma unroll
    for (int i = 0; i < 16; ++i) {
        const float df = qreg[i] - xsh[wv][tok][half * 16 + i];
        lacc = fmaf(df, df, lacc);
    }
    lacc += __shfl_down(lacc, 32);
    lacc += __shfl_down(lacc, 16); lacc += __shfl_down(lacc, 8);
    lacc += __shfl_down(lacc, 4);  lacc += __shfl_down(lacc, 2);
    lacc += __shfl_down(lacc, 1);
    if (l == 0) lossp[blockIdx.x * WAVES + wv] = lacc;

    #pragma unroll
    for (int i = 0; i < 16; ++i) xsh[wv][tok][half * 16 + i] = qreg[i];
    WAVE_FENCE();

    {
        const int c0 = half * 16;
        float a[16];
        #pragma unroll
        for (int i = 0; i < 16; ++i) a[i] = pb[c0 + i];
        #pragma unroll
        for (int d4 = 0; d4 < 8; ++d4) {
            const float q0 = xsh[wv][tok][d4*4+0], q1 = xsh[wv][tok][d4*4+1];
            const float q2 = xsh[wv][tok][d4*4+2], q3 = xsh[wv][tok][d4*4+3];
            #pragma unroll
            for (int i = 0; i < 16; ++i) {
                const float4 p4 = *(const float4*)(pw + (c0 + i) * D_ + d4 * 4);
                a[i] = fmaf(q0, p4.x, a[i]); a[i] = fmaf(q1, p4.y, a[i]);
                a[i] = fmaf(q2, p4.z, a[i]); a[i] = fmaf(q3, p4.w, a[i]);
            }
        }
        float* obase = out + (size_t)b * (C_ * HW_) + hw0 + tok;
        #pragma unroll
        for (int i = 0; i < 16; ++i) obase[(size_t)(c0 + i) * HW_] = a[i];
    }
}

// ---------- loss finalize (single block) ----------
__global__ __launch_bounds__(256)
void loss_final(const float* __restrict__ lossp, float* __restrict__ out)
{
    __shared__ float lsum[4];
    const int tid = threadIdx.x;
    float s = 0.f;
    for (int i = tid; i < 4096; i += 256) s += lossp[i];
    s += __shfl_down(s, 32); s += __shfl_down(s, 16);
    s += __shfl_down(s, 8);  s += __shfl_down(s, 4);
    s += __shfl_down(s, 2);  s += __shfl_down(s, 1);
    const int wv = tid >> 6, l = tid & 63;
    if (l == 0) lsum[wv] = s;
    __syncthreads();
    if (tid == 0)
        out[LOSS_OFF] = ((lsum[0] + lsum[1]) + (lsum[2] + lsum[3])) * (2.0f / (float)(NTOK * D_));
}

// ---------- fallback (round-1 monolithic) ----------
__global__ __launch_bounds__(256)
void vq_mono(const float* __restrict__ z,  const float* __restrict__ qw,
             const float* __restrict__ qb, const float* __restrict__ cb,
             const float* __restrict__ pw, const float* __restrict__ pb,
             float* __restrict__ out)
{
    __shared__ float cbn_s[K_];
    __shared__ float lsum[4];
    const int tid = threadIdx.x;
    for (int k = tid; k < K_; k += 256) {
        const float* row = cb + k * D_;
        float s = 0.f;
        #pragma unroll
        for (int d = 0; d < D_; ++d) s = fmaf(row[d], row[d], s);
        cbn_s[k] = s;
    }
    __syncthreads();
    const int token = blockIdx.x * 256 + tid;
    const int b = token >> 12, hw = token & (HW_ - 1);
    const float* zbase = z + (size_t)b * C_ * HW_ + hw;
    float zv[C_];
    #pragma unroll
    for (int c = 0; c < C_; ++c) zv[c] = zbase[(size_t)c * HW_];
    float xf[D_];
    #pragma unroll
    for (int d = 0; d < D_; ++d) {
        float a = qb[d];
        #pragma unroll
        for (int c = 0; c < C_; ++c) a = fmaf(zv[c], qw[d * C_ + c], a);
        xf[d] = a;
    }
    float best = 3.4e38f; int bi = 0;
    #pragma unroll 2
    for (int k = 0; k < K_; ++k) {
        const float* row = cb + k * D_;
        float p0 = 0.f, p1 = 0.f, p2 = 0.f, p3 = 0.f;
        #pragma unroll
        for (int d = 0; d < D_; d += 4) {
            p0 = fmaf(xf[d+0], row[d+0], p0); p1 = fmaf(xf[d+1], row[d+1], p1);
            p2 = fmaf(xf[d+2], row[d+2], p2); p3 = fmaf(xf[d+3], row[d+3], p3);
        }
        const float s = fmaf(-2.f, (p0+p1)+(p2+p3), cbn_s[k]);
        if (s < best) { best = s; bi = k; }
    }
    out[IDX_OFF + token] = (float)bi;
    const float* qrow = cb + (size_t)bi * D_;
    float qv[D_];
    #pragma unroll
    for (int d = 0; d < D_; ++d) qv[d] = qrow[d];
    float l = 0.f;
    #pragma unroll
    for (int d = 0; d < D_; ++d) { const float df = qv[d] - xf[d]; l = fmaf(df, df, l); }
    float* obase = out + (size_t)b * C_ * HW_ + hw;
    #pragma unroll
    for (int c = 0; c < C_; ++c) {
        float a = pb[c];
        #pragma unroll
        for (int d = 0; d < D_; ++d) a = fmaf(qv[d], pw[c * D_ + d], a);
        obase[(size_t)c * HW_] = a;
    }
    #pragma unroll
    for (int off = 32; off; off >>= 1) l += __shfl_down(l, off);
    const int wid = tid >> 6, lane = tid & 63;
    if (lane == 0) lsum[wid] = l;
    __syncthreads();
    if (tid == 0) {
        const float t = (lsum[0] + lsum[1]) + (lsum[2] + lsum[3]);
        atomicAdd(out + LOSS_OFF, t * (2.0f / (float)(NTOK * D_)));
    }
}

extern "C" void kernel_launch(void* const* d_in, const int* in_sizes, int n_in,
                              void* d_out, int out_size, void* d_ws, size_t ws_size,
                              hipStream_t stream) {
    (void)in_sizes; (void)n_in; (void)out_size;
    const float* z  = (const float*)d_in[0];
    const float* qw = (const float*)d_in[1];
    const float* qb = (const float*)d_in[2];
    const float* cb = (const float*)d_in[3];
    const float* pw = (const float*)d_in[4];
    const float* pb = (const float*)d_in[5];
    float* out = (float*)d_out;

    if (ws_size < (size_t)WS_NEEDED) {
        hipMemsetAsync((char*)d_out + (size_t)LOSS_OFF * sizeof(float), 0, sizeof(float), stream);
        vq_mono<<<NTOK / 256, 256, 0, stream>>>(z, qw, qb, cb, pw, pb, out);
        return;
    }
    char* ws = (char*)d_ws;
    float* cbn   = (float*)(ws + WS_CBN);
    short* cbhf  = (short*)(ws + WS_CBHF);
    short* cblf  = (short*)(ws + WS_CBLF);
    float* lossp = (float*)(ws + WS_LOSSP);

    prep_cb<<<2, 256, 0, stream>>>(cb, cbn, cbhf, cblf);

    // ---- ablation probes (1/8 grid, outputs fully overwritten by the real kernel below) ----
    vq_probe<1><<<32, 1024, 0, stream>>>(z, qw, qb, cb, pw, pb, cbhf, cblf, cbn, lossp, out);
    vq_probe<2><<<32, 1024, 0, stream>>>(z, qw, qb, cb, pw, pb, cbhf, cblf, cbn, lossp, out);
    vq_probe<3><<<32, 1024, 0, stream>>>(z, qw, qb, cb, pw, pb, cbhf, cblf, cbn, lossp, out);
    vq_probe<0><<<32, 1024, 0, stream>>>(z, qw, qb, cb, pw, pb, cbhf, cblf, cbn, lossp, out);

    // ---- real kernel (identical math to round 11) ----
    vq_probe<0><<<NTOK / (WAVES * 32), 1024, 0, stream>>>(z, qw, qb, cb, pw, pb, cbhf, cblf, cbn, lossp, out);
    loss_final<<<1, 256, 0, stream>>>(lossp, out);
}

// Round 14
// 84.707 us; speedup vs baseline: 3.1537x; 3.1537x over previous
//
#include <hip/hip_runtime.h>

// (B,C,H,W)=(32,32,64,64), D=32, K=512
#define C_    32
#define D_    32
#define K_    512
#define HW_   4096
#define NTOK  131072
#define IDX_OFF   4194304
#define LOSS_OFF  4325376
#define TAU   2e-4f

// ws: cbn @0 (2KB), cbhf @4096 (32KB frag-major f16 hi), cblf @36864 (32KB lo), lossp @69632 (16KB)
#define WS_CBN   0
#define WS_CBHF  4096
#define WS_CBLF  36864
#define WS_LOSSP 69632
#define WS_NEEDED 86016

typedef __attribute__((ext_vector_type(8))) _Float16 f16x8;
typedef __attribute__((ext_vector_type(8))) short    short8;
typedef __attribute__((ext_vector_type(4))) float    f32x4;

#define WAVE_FENCE() do { asm volatile("s_waitcnt lgkmcnt(0)" ::: "memory"); \
                          __builtin_amdgcn_sched_barrier(0); } while (0)

__device__ inline short f2h_hi(float v, float* rest) {
    const _Float16 h = (_Float16)v;
    *rest = v - (float)h;
    return __builtin_bit_cast(short, h);
}

// ---------- codebook: norms + f16 hi/lo split in FRAG-MAJOR layout ----------
__global__ __launch_bounds__(256)
void prep_cb(const float* __restrict__ cb, float* __restrict__ cbn,
             short* __restrict__ cbhf, short* __restrict__ cblf)
{
    const int k = blockIdx.x * 256 + threadIdx.x;   // grid=2 -> k in [0,512)
    const int nt = k >> 4, lr = k & 15;
    const float* row = cb + k * D_;
    float s = 0.f;
    short h[32], lo[32];
    #pragma unroll
    for (int d = 0; d < D_; ++d) {
        const float v = row[d]; s = fmaf(v, v, s);
        float r; h[d] = f2h_hi(v, &r);
        lo[d] = __builtin_bit_cast(short, (_Float16)r);
    }
    cbn[k] = s;
    #pragma unroll
    for (int j = 0; j < 4; ++j) {
        *(short8*)(cbhf + nt * 512 + (j * 16 + lr) * 8) = *(const short8*)(h  + 8 * j);
        *(short8*)(cblf + nt * 512 + (j * 16 + lr) * 8) = *(const short8*)(lo + 8 * j);
    }
}

// ---------- fused: 512 thr = 8 waves x 32 tokens; 67KB LDS -> 2 blocks/CU ----------
__global__ __launch_bounds__(512, 4)
void vq_fused(const float* __restrict__ z,  const float* __restrict__ qw,
              const float* __restrict__ qb, const float* __restrict__ cb,
              const float* __restrict__ pw, const float* __restrict__ pb,
              const short* __restrict__ cbhf, const short* __restrict__ cblf,
              const float* __restrict__ cbn, float* __restrict__ lossp,
              float* __restrict__ out)
{
    __shared__ __align__(16) short cbh_s[16384];   // 32 KB frag-major
    __shared__ __align__(16) short cbl_s[16384];   // 32 KB
    __shared__ float cbn_s[K_];                    // 2 KB
    __shared__ int   sidx[8][32];                  // 1 KB

    const int tid = threadIdx.x;
    const int wv = tid >> 6, l = tid & 63;
    const int lr = l & 15, lg = l >> 4;
    const int tok = l & 31, half = l >> 5;

    // ---- stage codebook to LDS (512 thr x 4 x 16B = 32KB per buffer — exact) ----
    #pragma unroll
    for (int i = 0; i < 4; ++i)
        ((float4*)cbh_s)[tid + 512 * i] = ((const float4*)cbhf)[tid + 512 * i];
    #pragma unroll
    for (int i = 0; i < 4; ++i)
        ((float4*)cbl_s)[tid + 512 * i] = ((const float4*)cblf)[tid + 512 * i];
    cbn_s[tid] = cbn[tid];
    __syncthreads();   // only block-wide barrier

    const int T0 = (blockIdx.x * 8 + wv) * 32;
    const int b = T0 >> 12, hw0 = T0 & (HW_ - 1);

    // ---- phase 1: conv, frag-native. Lane owns (token lr, d in [8lg,8lg+8)) and (token 16+lr, same d).
    //      z loaded coalesced (token = l&31); partner token's z via shfl_xor(16).
    float a0[8], a1[8];
    {
        const float* zbase = z + (size_t)b * (C_ * HW_) + hw0 + tok;
        float zv[C_];
        #pragma unroll
        for (int c = 0; c < C_; ++c) zv[c] = zbase[(size_t)c * HW_];

        const int d0 = lg * 8;
        #pragma unroll
        for (int j = 0; j < 8; ++j) { a0[j] = qb[d0 + j]; a1[j] = a0[j]; }

        const int podd = lg & 1;   // 1 if this lane's own token is 16+lr
        #pragma unroll
        for (int c4 = 0; c4 < 8; ++c4) {
            float zA[4], zB[4];
            #pragma unroll
            for (int u = 0; u < 4; ++u) {
                const float zo = __shfl_xor(zv[c4 * 4 + u], 16);   // partner token's z_c
                zA[u] = podd ? zo : zv[c4 * 4 + u];                // token lr
                zB[u] = podd ? zv[c4 * 4 + u] : zo;                // token 16+lr
            }
            #pragma unroll
            for (int j = 0; j < 8; ++j) {
                const float4 q4 = *(const float4*)(qw + (d0 + j) * C_ + c4 * 4);
                a0[j] = fmaf(zA[0], q4.x, a0[j]); a0[j] = fmaf(zA[1], q4.y, a0[j]);
                a0[j] = fmaf(zA[2], q4.z, a0[j]); a0[j] = fmaf(zA[3], q4.w, a0[j]);
                a1[j] = fmaf(zB[0], q4.x, a1[j]); a1[j] = fmaf(zB[1], q4.y, a1[j]);
                a1[j] = fmaf(zB[2], q4.z, a1[j]); a1[j] = fmaf(zB[3], q4.w, a1[j]);
            }
        }
    }

    // ---- f16 hi/lo A-fragments (in-register; a0/a1 stay live: exact xf for rescan/loss) ----
    short8 sh0, sl0, sh1, sl1;
    #pragma unroll
    for (int j = 0; j < 8; ++j) {
        float r0, r1;
        sh0[j] = f2h_hi(a0[j], &r0); sl0[j] = __builtin_bit_cast(short, (_Float16)r0);
        sh1[j] = f2h_hi(a1[j], &r1); sl1[j] = __builtin_bit_cast(short, (_Float16)r1);
    }
    const f16x8 ah0 = __builtin_bit_cast(f16x8, sh0);
    const f16x8 al0 = __builtin_bit_cast(f16x8, sl0);
    const f16x8 ah1 = __builtin_bit_cast(f16x8, sh1);
    const f16x8 al1 = __builtin_bit_cast(f16x8, sl1);

    // ---- phase 2: MFMA top-2 scan over 512 codes, B from LDS (R11-identical) ----
    float b1[8], b2[8]; int i1[8];
    #pragma unroll
    for (int s = 0; s < 8; ++s) { b1[s] = 3.4e38f; b2[s] = 3.4e38f; i1[s] = 0; }

    #pragma unroll 2
    for (int nt = 0; nt < 32; ++nt) {
        const f16x8 bh = __builtin_bit_cast(f16x8, *(const short8*)(cbh_s + nt * 512 + l * 8));
        const f16x8 bl = __builtin_bit_cast(f16x8, *(const short8*)(cbl_s + nt * 512 + l * 8));
        const float cn = cbn_s[nt * 16 + lr];
        f32x4 acc0 = {0.f,0.f,0.f,0.f}, acc1 = {0.f,0.f,0.f,0.f};
        acc0 = __builtin_amdgcn_mfma_f32_16x16x32_f16(ah0, bh, acc0, 0, 0, 0);
        acc0 = __builtin_amdgcn_mfma_f32_16x16x32_f16(ah0, bl, acc0, 0, 0, 0);
        acc0 = __builtin_amdgcn_mfma_f32_16x16x32_f16(al0, bh, acc0, 0, 0, 0);
        acc1 = __builtin_amdgcn_mfma_f32_16x16x32_f16(ah1, bh, acc1, 0, 0, 0);
        acc1 = __builtin_amdgcn_mfma_f32_16x16x32_f16(ah1, bl, acc1, 0, 0, 0);
        acc1 = __builtin_amdgcn_mfma_f32_16x16x32_f16(al1, bh, acc1, 0, 0, 0);
        const int n = nt * 16 + lr;
        #pragma unroll
        for (int r = 0; r < 4; ++r) {
            {
                const float d2 = fmaf(-2.f, acc0[r], cn);
                const bool lt1 = d2 < b1[r], lt2 = d2 < b2[r];
                b2[r] = lt1 ? b1[r] : (lt2 ? d2 : b2[r]);
                b1[r] = lt1 ? d2 : b1[r];
                i1[r] = lt1 ? n  : i1[r];
            }
            {
                const float d2 = fmaf(-2.f, acc1[r], cn);
                const bool lt1 = d2 < b1[4+r], lt2 = d2 < b2[4+r];
                b2[4+r] = lt1 ? b1[4+r] : (lt2 ? d2 : b2[4+r]);
                b1[4+r] = lt1 ? d2 : b1[4+r];
                i1[4+r] = lt1 ? n  : i1[4+r];
            }
        }
    }
    #pragma unroll
    for (int mk = 1; mk < 16; mk <<= 1) {
        #pragma unroll
        for (int s = 0; s < 8; ++s) {
            const float ob1 = __shfl_xor(b1[s], mk);
            const int   oi1 = __shfl_xor(i1[s], mk);
            const float ob2 = __shfl_xor(b2[s], mk);
            const bool take = (ob1 < b1[s]) || (ob1 == b1[s] && oi1 < i1[s]);
            const float loser = take ? b1[s] : ob1;
            b1[s] = take ? ob1 : b1[s];
            i1[s] = take ? oi1 : i1[s];
            b2[s] = fminf(fminf(b2[s], ob2), loser);
        }
    }
    #pragma unroll
    for (int s = 0; s < 8; ++s) {
        if (lr == s) {
            const int tokW = (s >> 2) * 16 + lg * 4 + (s & 3);
            sidx[wv][tokW] = i1[s] | (((b2[s] - b1[s]) < TAU) ? 512 : 0);
        }
    }
    WAVE_FENCE();

    // ---- phase 3: exact fp32 rescan of flagged tokens; xf via shfl of EXACT a0/a1 ----
    {
        const int sv = sidx[wv][tok];
        unsigned long long m = __ballot((l < 32) && (sv & 512));
        while (m) {
            const int j = __ffsll(m) - 1; m &= m - 1;
            float xfj[D_];
            if (j < 16) {
                #pragma unroll
                for (int d = 0; d < D_; ++d)
                    xfj[d] = __shfl(a0[d & 7], (j & 15) + 16 * (d >> 3));
            } else {
                #pragma unroll
                for (int d = 0; d < D_; ++d)
                    xfj[d] = __shfl(a1[d & 7], (j & 15) + 16 * (d >> 3));
            }
            float bb = 3.4e38f; int bi = 0;
            #pragma unroll
            for (int p = 0; p < 8; ++p) {
                const int c = l + 64 * p;
                const float* row = cb + (size_t)c * D_;
                float p0 = 0.f, p1 = 0.f, p2 = 0.f, p3 = 0.f;
                #pragma unroll
                for (int d = 0; d < D_; d += 4) {
                    p0 = fmaf(xfj[d],   row[d],   p0); p1 = fmaf(xfj[d+1], row[d+1], p1);
                    p2 = fmaf(xfj[d+2], row[d+2], p2); p3 = fmaf(xfj[d+3], row[d+3], p3);
                }
                const float dd = fmaf(-2.f, (p0 + p1) + (p2 + p3), cbn_s[c]);
                if (dd < bb) { bb = dd; bi = c; }
            }
            #pragma unroll
            for (int s = 1; s < 64; s <<= 1) {
                const float ob = __shfl_xor(bb, s); const int oi = __shfl_xor(bi, s);
                if (ob < bb || (ob == bb && oi < bi)) { bb = ob; bi = oi; }
            }
            if (l == j) sidx[wv][j] = bi;
        }
    }
    WAVE_FENCE();
    const int myidx = sidx[wv][tok] & 511;

    // ---- idx write ----
    if (l < 32) out[IDX_OFF + T0 + l] = (float)(sidx[wv][l] & 511);

    // ---- loss in frag layout: lane's 2 cells, exact fp32 a0/a1 ----
    {
        const int d0 = lg * 8;
        const int iA = sidx[wv][lr] & 511;
        const int iB = sidx[wv][16 + lr] & 511;
        const float4 qa = *(const float4*)(cb + (size_t)iA * D_ + d0);
        const float4 qa2 = *(const float4*)(cb + (size_t)iA * D_ + d0 + 4);
        const float4 qc = *(const float4*)(cb + (size_t)iB * D_ + d0);
        const float4 qc2 = *(const float4*)(cb + (size_t)iB * D_ + d0 + 4);
        float qA[8] = {qa.x, qa.y, qa.z, qa.w, qa2.x, qa2.y, qa2.z, qa2.w};
        float qB[8] = {qc.x, qc.y, qc.z, qc.w, qc2.x, qc2.y, qc2.z, qc2.w};
        float lacc = 0.f;
        #pragma unroll
        for (int j = 0; j < 8; ++j) {
            const float dA = qA[j] - a0[j], dB = qB[j] - a1[j];
            lacc = fmaf(dA, dA, lacc); lacc = fmaf(dB, dB, lacc);
        }
        lacc += __shfl_down(lacc, 32); lacc += __shfl_down(lacc, 16);
        lacc += __shfl_down(lacc, 8);  lacc += __shfl_down(lacc, 4);
        lacc += __shfl_down(lacc, 2);  lacc += __shfl_down(lacc, 1);
        if (l == 0) lossp[blockIdx.x * 8 + wv] = lacc;
    }

    // ---- post conv: lane=(tok,half) gathers its 16 q dims, partner half via shfl_xor(32) ----
    {
        float qreg[16];
        const float4* qrow = (const float4*)(cb + (size_t)myidx * D_ + half * 16);
        #pragma unroll
        for (int d4 = 0; d4 < 4; ++d4) {
            const float4 t = qrow[d4];
            qreg[4*d4+0] = t.x; qreg[4*d4+1] = t.y; qreg[4*d4+2] = t.z; qreg[4*d4+3] = t.w;
        }
        float qlo[16], qhi[16];
        #pragma unroll
        for (int i = 0; i < 16; ++i) {
            const float qo = __shfl_xor(qreg[i], 32);   // partner lane = (tok, 1-half)
            qlo[i] = half ? qo : qreg[i];               // dims 0..15
            qhi[i] = half ? qreg[i] : qo;               // dims 16..31
        }
        const int c0 = half * 16;
        float a[16];
        #pragma unroll
        for (int i = 0; i < 16; ++i) a[i] = pb[c0 + i];
        #pragma unroll
        for (int d4 = 0; d4 < 8; ++d4) {
            const float q0 = (d4 < 4) ? qlo[d4*4+0] : qhi[(d4-4)*4+0];
            const float q1 = (d4 < 4) ? qlo[d4*4+1] : qhi[(d4-4)*4+1];
            const float q2 = (d4 < 4) ? qlo[d4*4+2] : qhi[(d4-4)*4+2];
            const float q3 = (d4 < 4) ? qlo[d4*4+3] : qhi[(d4-4)*4+3];
            #pragma unroll
            for (int i = 0; i < 16; ++i) {
                const float4 p4 = *(const float4*)(pw + (c0 + i) * D_ + d4 * 4);
                a[i] = fmaf(q0, p4.x, a[i]); a[i] = fmaf(q1, p4.y, a[i]);
                a[i] = fmaf(q2, p4.z, a[i]); a[i] = fmaf(q3, p4.w, a[i]);
            }
        }
        float* obase = out + (size_t)b * (C_ * HW_) + hw0 + tok;
        #pragma unroll
        for (int i = 0; i < 16; ++i) obase[(size_t)(c0 + i) * HW_] = a[i];
    }
}

// ---------- loss finalize (single block) ----------
__global__ __launch_bounds__(256)
void loss_final(const float* __restrict__ lossp, float* __restrict__ out)
{
    __shared__ float lsum[4];
    const int tid = threadIdx.x;
    float s = 0.f;
    for (int i = tid; i < 4096; i += 256) s += lossp[i];
    s += __shfl_down(s, 32); s += __shfl_down(s, 16);
    s += __shfl_down(s, 8);  s += __shfl_down(s, 4);
    s += __shfl_down(s, 2);  s += __shfl_down(s, 1);
    const int wv = tid >> 6, l = tid & 63;
    if (l == 0) lsum[wv] = s;
    __syncthreads();
    if (tid == 0)
        out[LOSS_OFF] = ((lsum[0] + lsum[1]) + (lsum[2] + lsum[3])) * (2.0f / (float)(NTOK * D_));
}

// ---------- fallback (round-1 monolithic) ----------
__global__ __launch_bounds__(256)
void vq_mono(const float* __restrict__ z,  const float* __restrict__ qw,
             const float* __restrict__ qb, const float* __restrict__ cb,
             const float* __restrict__ pw, const float* __restrict__ pb,
             float* __restrict__ out)
{
    __shared__ float cbn_s[K_];
    __shared__ float lsum[4];
    const int tid = threadIdx.x;
    for (int k = tid; k < K_; k += 256) {
        const float* row = cb + k * D_;
        float s = 0.f;
        #pragma unroll
        for (int d = 0; d < D_; ++d) s = fmaf(row[d], row[d], s);
        cbn_s[k] = s;
    }
    __syncthreads();
    const int token = blockIdx.x * 256 + tid;
    const int b = token >> 12, hw = token & (HW_ - 1);
    const float* zbase = z + (size_t)b * C_ * HW_ + hw;
    float zv[C_];
    #pragma unroll
    for (int c = 0; c < C_; ++c) zv[c] = zbase[(size_t)c * HW_];
    float xf[D_];
    #pragma unroll
    for (int d = 0; d < D_; ++d) {
        float a = qb[d];
        #pragma unroll
        for (int c = 0; c < C_; ++c) a = fmaf(zv[c], qw[d * C_ + c], a);
        xf[d] = a;
    }
    float best = 3.4e38f; int bi = 0;
    #pragma unroll 2
    for (int k = 0; k < K_; ++k) {
        const float* row = cb + k * D_;
        float p0 = 0.f, p1 = 0.f, p2 = 0.f, p3 = 0.f;
        #pragma unroll
        for (int d = 0; d < D_; d += 4) {
            p0 = fmaf(xf[d+0], row[d+0], p0); p1 = fmaf(xf[d+1], row[d+1], p1);
            p2 = fmaf(xf[d+2], row[d+2], p2); p3 = fmaf(xf[d+3], row[d+3], p3);
        }
        const float s = fmaf(-2.f, (p0+p1)+(p2+p3), cbn_s[k]);
        if (s < best) { best = s; bi = k; }
    }
    out[IDX_OFF + token] = (float)bi;
    const float* qrow = cb + (size_t)bi * D_;
    float qv[D_];
    #pragma unroll
    for (int d = 0; d < D_; ++d) qv[d] = qrow[d];
    float l = 0.f;
    #pragma unroll
    for (int d = 0; d < D_; ++d) { const float df = qv[d] - xf[d]; l = fmaf(df, df, l); }
    float* obase = out + (size_t)b * C_ * HW_ + hw;
    #pragma unroll
    for (int c = 0; c < C_; ++c) {
        float a = pb[c];
        #pragma unroll
        for (int d = 0; d < D_; ++d) a = fmaf(qv[d], pw[c * D_ + d], a);
        obase[(size_t)c * HW_] = a;
    }
    #pragma unroll
    for (int off = 32; off; off >>= 1) l += __shfl_down(l, off);
    const int wid = tid >> 6, lane = tid & 63;
    if (lane == 0) lsum[wid] = l;
    __syncthreads();
    if (tid == 0) {
        const float t = (lsum[0] + lsum[1]) + (lsum[2] + lsum[3]);
        atomicAdd(out + LOSS_OFF, t * (2.0f / (float)(NTOK * D_)));
    }
}

extern "C" void kernel_launch(void* const* d_in, const int* in_sizes, int n_in,
                              void* d_out, int out_size, void* d_ws, size_t ws_size,
                              hipStream_t stream) {
    (void)in_sizes; (void)n_in; (void)out_size;
    const float* z  = (const float*)d_in[0];
    const float* qw = (const float*)d_in[1];
    const float* qb = (const float*)d_in[2];
    const float* cb = (const float*)d_in[3];
    const float* pw = (const float*)d_in[4];
    const float* pb = (const float*)d_in[5];
    float* out = (float*)d_out;

    if (ws_size < (size_t)WS_NEEDED) {
        hipMemsetAsync((char*)d_out + (size_t)LOSS_OFF * sizeof(float), 0, sizeof(float), stream);
        vq_mono<<<NTOK / 256, 256, 0, stream>>>(z, qw, qb, cb, pw, pb, out);
        return;
    }
    char* ws = (char*)d_ws;
    float* cbn   = (float*)(ws + WS_CBN);
    short* cbhf  = (short*)(ws + WS_CBHF);
    short* cblf  = (short*)(ws + WS_CBLF);
    float* lossp = (float*)(ws + WS_LOSSP);

    prep_cb<<<2, 256, 0, stream>>>(cb, cbn, cbhf, cblf);
    vq_fused<<<512, 512, 0, stream>>>(z, qw, qb, cb, pw, pb, cbhf, cblf, cbn, lossp, out);
    loss_final<<<1, 256, 0, stream>>>(lossp, out);
}